// Round 13
// baseline (438.194 us; speedup 1.0000x reference)
//
#include <hip/hip_runtime.h>
#include <hip/hip_bf16.h>
#include <cstdint>

constexpr int N_NODES = 50000;
constexpr int N_EDGES = 800000;
constexpr int F_IN    = 128;
constexpr int F_HID   = 256;
constexpr int N_COLS  = 256;
constexpr int M_PAD   = 50176;   // 392 * 128
constexpr int NB_F2BF = (N_NODES * F_IN / 4) / 256;  // 6250 (exact)

// CSR build via bucketed counting sort
constexpr int EPB     = 4096;
constexpr int NB_PART = (N_EDGES + EPB - 1) / EPB;    // 196
constexpr int NBUCK   = (N_NODES + 255) / 256;        // 196

typedef unsigned short u16;
typedef u16   ushort4v __attribute__((ext_vector_type(4)));
typedef u16   ushort8v __attribute__((ext_vector_type(8)));
typedef __bf16 bf16x8  __attribute__((ext_vector_type(8)));
typedef float  f32x4   __attribute__((ext_vector_type(4)));

__device__ __forceinline__ float bf2f(u16 u) {
    return __uint_as_float(((uint32_t)u) << 16);
}
__device__ __forceinline__ u16 f2bf(float f) {
    uint32_t u = __float_as_uint(f);
    uint32_t r = u + 0x7FFFu + ((u >> 16) & 1u);   // RNE
    return (u16)(r >> 16);
}

// async global->LDS, 16B per lane. LDS dest is wave-uniform base; HW adds lane*16.
__device__ __forceinline__ void gll16(const void* g, void* l) {
    __builtin_amdgcn_global_load_lds(
        (const __attribute__((address_space(1))) uint32_t*)(uintptr_t)g,
        (__attribute__((address_space(3))) uint32_t*)(uintptr_t)l,
        16, 0, 0);
}

// ---------------------------------------------------------------------------
// P1 + prep fused: blocks [0,NB_PART) = dst-bucket histogram;
// rest = fp32->bf16 conversions (x, W1^T, W2^T). Independent outputs.
// ---------------------------------------------------------------------------
__global__ __launch_bounds__(256) void hist_prep_kernel(const int* __restrict__ dst,
                                                        int* __restrict__ hist,
                                                        const float* __restrict__ x,
                                                        u16* __restrict__ xb,
                                                        const float* __restrict__ W1,
                                                        u16* __restrict__ W1t,
                                                        const float* __restrict__ W2,
                                                        u16* __restrict__ W2t) {
    const int b = blockIdx.x;
    const int t = threadIdx.x;
    if (b < NB_PART) {
        __shared__ int h[256];
        h[t] = 0;
        __syncthreads();
        const int base = b * EPB;
        #pragma unroll
        for (int i = 0; i < EPB / 256; ++i) {
            const int e = base + i * 256 + t;
            if (e < N_EDGES) atomicAdd(&h[dst[e] >> 8], 1);
        }
        __syncthreads();
        hist[b * 256 + t] = h[t];
    } else if (b < NB_PART + NB_F2BF) {
        const int i = (b - NB_PART) * 256 + t;   // float4 index
        float4 v = *reinterpret_cast<const float4*>(&x[(size_t)i * 4]);
        ushort4v o;
        o.x = f2bf(v.x); o.y = f2bf(v.y); o.z = f2bf(v.z); o.w = f2bf(v.w);
        *reinterpret_cast<ushort4v*>(&xb[(size_t)i * 4]) = o;
    } else if (b < NB_PART + NB_F2BF + 256) {
        const int n = b - (NB_PART + NB_F2BF);
        W1t[(size_t)n * 256 + t] = f2bf(W1[(size_t)t * N_COLS + n]);
    } else {
        const int n = b - (NB_PART + NB_F2BF + 256);
        #pragma unroll
        for (int kk = 0; kk < 2; ++kk) {
            const int k = kk * 256 + t;
            W2t[(size_t)n * 512 + k] = f2bf(W2[(size_t)k * N_COLS + n]);
        }
    }
}

// S1: per-bin scan across blocks.
__global__ __launch_bounds__(256) void colscan_kernel(int* __restrict__ hist,
                                                      int* __restrict__ bin_tot) {
    __shared__ int s[256];
    const int b = blockIdx.x;
    const int t = threadIdx.x;
    const int v = (t < NB_PART) ? hist[t * 256 + b] : 0;
    s[t] = v;
    __syncthreads();
    #pragma unroll
    for (int o = 1; o < 256; o <<= 1) {
        int tv = 0;
        if (t >= o) tv = s[t - o];
        __syncthreads();
        s[t] += tv;
        __syncthreads();
    }
    if (t < NB_PART) hist[t * 256 + b] = s[t] - v;
    if (t == 255) bin_tot[b] = s[255];
}

// S2: exclusive scan of bin totals -> bin_base; also zero the degree hist.
__global__ __launch_bounds__(256) void binscan_kernel(const int* __restrict__ bin_tot,
                                                      int* __restrict__ bin_base,
                                                      int* __restrict__ row_ptr,
                                                      int* __restrict__ dhist) {
    __shared__ int s[256];
    const int t = threadIdx.x;
    const int v = (t < NBUCK) ? bin_tot[t] : 0;
    s[t] = v;
    __syncthreads();
    #pragma unroll
    for (int o = 1; o < 256; o <<= 1) {
        int tv = 0;
        if (t >= o) tv = s[t - o];
        __syncthreads();
        s[t] += tv;
        __syncthreads();
    }
    bin_base[t] = s[t] - v;
    dhist[t] = 0;
    if (t == 0) row_ptr[N_NODES] = N_EDGES;
}

// P2: partition edges into bucket-contiguous ebuf.
// Packed entry: src (16b) | (dst & 255) << 16  — src < 65536 guaranteed.
__global__ __launch_bounds__(256) void scatter_kernel(const int* __restrict__ src,
                                                      const int* __restrict__ dst,
                                                      const int* __restrict__ hist,
                                                      const int* __restrict__ bin_base,
                                                      int* __restrict__ ebuf) {
    __shared__ int cur[256];
    const int t = threadIdx.x;
    cur[t] = bin_base[t] + hist[blockIdx.x * 256 + t];
    __syncthreads();
    const int base = blockIdx.x * EPB;
    #pragma unroll
    for (int i = 0; i < EPB / 256; ++i) {
        const int e = base + i * 256 + t;
        if (e < N_EDGES) {
            const int d = dst[e];
            const int pos = atomicAdd(&cur[d >> 8], 1);
            ebuf[pos] = (src[e] & 0xFFFF) | ((d & 255) << 16);
        }
    }
}

// P3: one block per bucket: deg-count -> scan -> row_ptr/inv_deg -> col fill.
// Also feeds the global degree histogram (for the degree sort).
__global__ __launch_bounds__(256) void bucket_fill_kernel(const int* __restrict__ ebuf,
                                                          const int* __restrict__ bin_base,
                                                          int* __restrict__ row_ptr,
                                                          float* __restrict__ inv_deg,
                                                          int* __restrict__ col,
                                                          int* __restrict__ dhist) {
    __shared__ int cnt[256];
    __shared__ int scn[256];
    __shared__ int cur[256];
    const int blk = blockIdx.x;
    const int t = threadIdx.x;
    const int ebeg = bin_base[blk];
    const int eend = bin_base[blk + 1];
    const int nb0 = blk << 8;

    cnt[t] = 0;
    __syncthreads();
    for (int e = ebeg + t; e < eend; e += 256)
        atomicAdd(&cnt[(ebuf[e] >> 16) & 255], 1);
    __syncthreads();
    const int d = cnt[t];
    scn[t] = d;
    __syncthreads();
    #pragma unroll
    for (int o = 1; o < 256; o <<= 1) {
        int tv = 0;
        if (t >= o) tv = scn[t - o];
        __syncthreads();
        scn[t] += tv;
        __syncthreads();
    }
    const int off = scn[t] - d;
    const int n = nb0 + t;
    if (n < N_NODES) {
        row_ptr[n] = ebeg + off;
        inv_deg[n] = (d > 0) ? (1.0f / (float)d) : 0.0f;
        atomicAdd(&dhist[d < 255 ? d : 255], 1);
    }
    cur[t] = off;
    __syncthreads();
    for (int e = ebeg + t; e < eend; e += 256) {
        const int p = ebuf[e];
        col[ebeg + atomicAdd(&cur[(p >> 16) & 255], 1)] = p & 0xFFFF;
    }
}

// D1: exclusive scan of degree histogram -> dcursor (write cursors per bin).
__global__ __launch_bounds__(256) void dscan_kernel(const int* __restrict__ dhist,
                                                    int* __restrict__ dcursor) {
    __shared__ int s[256];
    const int t = threadIdx.x;
    const int v = dhist[t];
    s[t] = v;
    __syncthreads();
    #pragma unroll
    for (int o = 1; o < 256; o <<= 1) {
        int tv = 0;
        if (t >= o) tv = s[t - o];
        __syncthreads();
        s[t] += tv;
        __syncthreads();
    }
    dcursor[t] = s[t] - v;
}

// D2: scatter node ids into degree-sorted order[].
__global__ __launch_bounds__(256) void dorder_kernel(const int* __restrict__ rp,
                                                     int* __restrict__ dcursor,
                                                     int* __restrict__ order) {
    const int n = blockIdx.x * 256 + threadIdx.x;
    if (n < N_NODES) {
        int d = rp[n + 1] - rp[n];
        if (d > 255) d = 255;
        const int pos = atomicAdd(&dcursor[d], 1);
        order[pos] = n;
    }
}

// ---------------------------------------------------------------------------
// Column-sliced, XCD-pinned, DEGREE-SORTED mean aggregation.
// order[] groups equal-degree nodes -> the 8 node-slots of a wave have
// near-equal loop lengths -> minimal exec-mask divergence in the edge loop.
// Per-node arithmetic identical to prior rounds.
// ---------------------------------------------------------------------------
template <int F, int SLICES>
__global__ __launch_bounds__(256) void agg_mean_sliced(const u16* __restrict__ feat,
                                                       const int* __restrict__ rp,
                                                       const int* __restrict__ col,
                                                       const float* __restrict__ invd,
                                                       const int* __restrict__ order,
                                                       u16* __restrict__ out) {
    constexpr int SC  = F / SLICES;                    // 64 cols = 128B slice
    static_assert(SC == 64, "slice must be one 128B line");
    constexpr int LPN = SC / 8;                        // 8 lanes per node
    constexpr int NPB = 256 / LPN;                     // 32 nodes per block
    constexpr int XPS = 8 / SLICES;                    // XCDs per slice
    constexpr int NCHUNK = (N_NODES + NPB - 1) / NPB;  // 1563
    constexpr int CPX    = (NCHUNK + XPS - 1) / XPS;
    const int bid  = blockIdx.x;
    const int x    = bid & 7;
    const int s    = x / XPS;
    const int part = x % XPS;
    const int chunk = part * CPX + (bid >> 3);
    const int slot = threadIdx.x / LPN;
    const int ln   = threadIdx.x % LPN;
    const int gs = chunk * NPB + slot;
    if (gs >= N_NODES) return;
    const int n = order[gs];

    const u16* ft = feat + s * SC + ln * 8;
    const int beg = rp[n], end = rp[n + 1];
    float acc0[8] = {}, acc1[8] = {};
    int e = beg;
    for (; e + 3 < end; e += 4) {
        int nb0 = col[e];
        int nb1 = col[e + 1];
        int nb2 = col[e + 2];
        int nb3 = col[e + 3];
        ushort8v v0 = *reinterpret_cast<const ushort8v*>(&ft[(size_t)nb0 * F]);
        ushort8v v1 = *reinterpret_cast<const ushort8v*>(&ft[(size_t)nb1 * F]);
        ushort8v v2 = *reinterpret_cast<const ushort8v*>(&ft[(size_t)nb2 * F]);
        ushort8v v3 = *reinterpret_cast<const ushort8v*>(&ft[(size_t)nb3 * F]);
        #pragma unroll
        for (int j = 0; j < 8; ++j) acc0[j] += bf2f(v0[j]);
        #pragma unroll
        for (int j = 0; j < 8; ++j) acc1[j] += bf2f(v1[j]);
        #pragma unroll
        for (int j = 0; j < 8; ++j) acc0[j] += bf2f(v2[j]);
        #pragma unroll
        for (int j = 0; j < 8; ++j) acc1[j] += bf2f(v3[j]);
    }
    if (e + 1 < end) {
        int nb0 = col[e];
        int nb1 = col[e + 1];
        ushort8v v0 = *reinterpret_cast<const ushort8v*>(&ft[(size_t)nb0 * F]);
        ushort8v v1 = *reinterpret_cast<const ushort8v*>(&ft[(size_t)nb1 * F]);
        #pragma unroll
        for (int j = 0; j < 8; ++j) acc0[j] += bf2f(v0[j]);
        #pragma unroll
        for (int j = 0; j < 8; ++j) acc1[j] += bf2f(v1[j]);
        e += 2;
    }
    if (e < end) {
        ushort8v v = *reinterpret_cast<const ushort8v*>(&ft[(size_t)col[e] * F]);
        #pragma unroll
        for (int j = 0; j < 8; ++j) acc0[j] += bf2f(v[j]);
    }
    const float sc = invd[n];
    ushort8v o;
    #pragma unroll
    for (int j = 0; j < 8; ++j) o[j] = f2bf((acc0[j] + acc1[j]) * sc);
    *reinterpret_cast<ushort8v*>(&out[(size_t)n * F + s * SC + ln * 8]) = o;
}

// ---------------------------------------------------------------------------
// C = relu([A1 | A2] @ W + b), bf16 MFMA, BK=64 + both-sides XOR swizzle
// (round-12 verbatim — validated).
// ---------------------------------------------------------------------------
template <int K1, bool OUT_BF16>
__global__ __launch_bounds__(256) void gemm_bt_bf16(const u16* __restrict__ A1,
                                                    const u16* __restrict__ A2,
                                                    const u16* __restrict__ Bt,
                                                    const float* __restrict__ bias,
                                                    void* __restrict__ Cout, int M) {
    constexpr int K = 2 * K1;
    __shared__ u16 As[128 * 64];
    __shared__ u16 Bs[128 * 64];

    const int t  = threadIdx.x;
    const int wv = t >> 6;
    const int l  = t & 63;
    const int g  = blockIdx.x >> 4;
    const int r  = blockIdx.x & 15;
    const int m0 = (g * 8 + (r & 7)) * 128;
    const int n0 = (r >> 3) * 128;

    const int srow = l >> 3;
    const int sjj  = ((l & 7) ^ srow) * 8;

    const int lr  = l & 15;
    const int l4  = l >> 4;
    const int wr  = (wv >> 1) * 64;
    const int wc  = (wv & 1) * 64;
    const int swz = lr & 7;

    f32x4 acc[4][4] = {};

    #pragma unroll 1
    for (int kt = 0; kt < K / 64; ++kt) {
        const int kg = kt * 64;
        const u16* Ab;
        int ka;
        if (kg < K1) { Ab = A1; ka = kg; }
        else         { Ab = A2; ka = kg - K1; }

        #pragma unroll
        for (int i = 0; i < 4; ++i) {
            const int rowg = wv * 32 + i * 8;
            gll16(&Ab[(size_t)(m0 + rowg + srow) * K1 + ka + sjj], &As[rowg * 64]);
            gll16(&Bt[(size_t)(n0 + rowg + srow) * K  + kg + sjj], &Bs[rowg * 64]);
        }
        __syncthreads();

        #pragma unroll
        for (int kk2 = 0; kk2 < 2; ++kk2) {
            const int jc = ((kk2 * 4 + l4) ^ swz) * 8;
            bf16x8 af[4], bfr[4];
            #pragma unroll
            for (int m = 0; m < 4; ++m)
                af[m] = *reinterpret_cast<const bf16x8*>(&As[(wr + m * 16 + lr) * 64 + jc]);
            #pragma unroll
            for (int n = 0; n < 4; ++n)
                bfr[n] = *reinterpret_cast<const bf16x8*>(&Bs[(wc + n * 16 + lr) * 64 + jc]);
            #pragma unroll
            for (int m = 0; m < 4; ++m)
                #pragma unroll
                for (int n = 0; n < 4; ++n)
                    acc[m][n] = __builtin_amdgcn_mfma_f32_16x16x32_bf16(af[m], bfr[n], acc[m][n], 0, 0, 0);
        }
        __syncthreads();
    }

    const int orow = (l >> 4) * 4;
    float bcol[4];
    #pragma unroll
    for (int n = 0; n < 4; ++n) bcol[n] = bias[n0 + wc + n * 16 + lr];

    #pragma unroll
    for (int m = 0; m < 4; ++m) {
        #pragma unroll
        for (int r2 = 0; r2 < 4; ++r2) {
            const int row = m0 + wr + m * 16 + orow + r2;
            if (row < M) {
                #pragma unroll
                for (int n = 0; n < 4; ++n) {
                    const int cg = n0 + wc + n * 16 + lr;
                    float v = fmaxf(acc[m][n][r2] + bcol[n], 0.f);
                    if (OUT_BF16)
                        ((u16*)Cout)[(size_t)row * N_COLS + cg] = f2bf(v);
                    else
                        ((float*)Cout)[(size_t)row * N_COLS + cg] = v;
                }
            }
        }
    }
}

// ---------------------------------------------------------------------------
// Host launch
// ---------------------------------------------------------------------------
extern "C" void kernel_launch(void* const* d_in, const int* in_sizes, int n_in,
                              void* d_out, int out_size, void* d_ws, size_t ws_size,
                              hipStream_t stream) {
    const float* x   = (const float*)d_in[0];
    const int*   src = (const int*)d_in[1];
    const int*   dst = (const int*)d_in[2];
    const float* W1  = (const float*)d_in[3];
    const float* b1  = (const float*)d_in[4];
    const float* W2  = (const float*)d_in[5];
    const float* b2  = (const float*)d_in[6];
    float* out = (float*)d_out;

    char* ws = (char*)d_ws;
    size_t off = 0;
    auto carve = [&](size_t bytes) {
        char* p = ws + off;
        off = (off + bytes + 255) & ~(size_t)255;
        return p;
    };
    int*   row_ptr  = (int*)carve(sizeof(int) * (N_NODES + 1));
    float* inv_deg  = (float*)carve(sizeof(float) * N_NODES);
    int*   col      = (int*)carve(sizeof(int) * N_EDGES);
    int*   hist     = (int*)carve(sizeof(int) * NB_PART * 256);
    int*   bin_tot  = (int*)carve(sizeof(int) * 256);
    int*   bin_base = (int*)carve(sizeof(int) * 256);
    int*   dhist    = (int*)carve(sizeof(int) * 256);
    int*   dcursor  = (int*)carve(sizeof(int) * 256);
    int*   order    = (int*)carve(sizeof(int) * N_NODES);
    int*   ebuf     = (int*)carve(sizeof(int) * N_EDGES);
    u16*   xb       = (u16*)carve(sizeof(u16) * (size_t)M_PAD * F_IN);
    u16*   xnb      = (u16*)carve(sizeof(u16) * (size_t)M_PAD * F_IN);
    u16*   h1b      = (u16*)carve(sizeof(u16) * (size_t)M_PAD * F_HID);
    u16*   h1nb     = (u16*)carve(sizeof(u16) * (size_t)M_PAD * F_HID);
    u16*   W1t      = (u16*)carve(sizeof(u16) * 256 * 256);
    u16*   W2t      = (u16*)carve(sizeof(u16) * 256 * 512);

    // --- CSR build + conversions ---
    hist_prep_kernel<<<dim3(NB_PART + NB_F2BF + 512), 256, 0, stream>>>(
        dst, hist, x, xb, W1, W1t, W2, W2t);
    colscan_kernel<<<dim3(NBUCK), 256, 0, stream>>>(hist, bin_tot);
    binscan_kernel<<<dim3(1), 256, 0, stream>>>(bin_tot, bin_base, row_ptr, dhist);
    scatter_kernel<<<dim3(NB_PART), 256, 0, stream>>>(src, dst, hist, bin_base, ebuf);
    bucket_fill_kernel<<<dim3(NBUCK), 256, 0, stream>>>(ebuf, bin_base, row_ptr, inv_deg, col, dhist);

    // --- degree sort (node order for divergence-free agg waves) ---
    dscan_kernel<<<dim3(1), 256, 0, stream>>>(dhist, dcursor);
    dorder_kernel<<<dim3(NBUCK), 256, 0, stream>>>(row_ptr, dcursor, order);

    // --- Layer 1: 64-col slices (2 slices, 4 XCDs each) ---
    {
        constexpr int NPB = 32, XPS = 4;
        constexpr int CPX = (((N_NODES + NPB - 1) / NPB) + XPS - 1) / XPS;   // 391
        agg_mean_sliced<F_IN, 2><<<dim3(8 * CPX), 256, 0, stream>>>(
            xb, row_ptr, col, inv_deg, order, xnb);
    }
    gemm_bt_bf16<128, true><<<dim3(784), 256, 0, stream>>>(xb, xnb, W1t, b1, h1b, N_NODES);

    // --- Layer 2: 64-col slices (4 slices, 2 XCDs each) ---
    {
        constexpr int NPB = 32, XPS = 2;
        constexpr int CPX = (((N_NODES + NPB - 1) / NPB) + XPS - 1) / XPS;   // 782
        agg_mean_sliced<F_HID, 4><<<dim3(8 * CPX), 256, 0, stream>>>(
            h1b, row_ptr, col, inv_deg, order, h1nb);
    }
    gemm_bt_bf16<256, false><<<dim3(784), 256, 0, stream>>>(h1b, h1nb, W2t, b2, out, N_NODES);
}

// Round 14
// 182.373 us; speedup vs baseline: 2.4027x; 2.4027x over previous
//
#include <hip/hip_runtime.h>
#include <hip/hip_bf16.h>
#include <cstdint>

constexpr int N_NODES = 50000;
constexpr int N_EDGES = 800000;
constexpr int F_IN    = 128;
constexpr int F_HID   = 256;
constexpr int N_COLS  = 256;
constexpr int M_PAD   = 50176;   // 392 * 128
constexpr int NB_F2BF = (N_NODES * F_IN / 4) / 256;  // 6250 (exact)

constexpr int EPB     = 4096;
constexpr int NB_PART = (N_EDGES + EPB - 1) / EPB;    // 196
constexpr int NBUCK   = (N_NODES + 255) / 256;        // 196

typedef unsigned short u16;
typedef u16   ushort4v __attribute__((ext_vector_type(4)));
typedef u16   ushort8v __attribute__((ext_vector_type(8)));
typedef __bf16 bf16x8  __attribute__((ext_vector_type(8)));
typedef float  f32x4   __attribute__((ext_vector_type(4)));

__device__ __forceinline__ float bf2f(u16 u) {
    return __uint_as_float(((uint32_t)u) << 16);
}
__device__ __forceinline__ u16 f2bf(float f) {
    uint32_t u = __float_as_uint(f);
    uint32_t r = u + 0x7FFFu + ((u >> 16) & 1u);   // RNE
    return (u16)(r >> 16);
}

__device__ __forceinline__ void gll16(const void* g, void* l) {
    __builtin_amdgcn_global_load_lds(
        (const __attribute__((address_space(1))) uint32_t*)(uintptr_t)g,
        (__attribute__((address_space(3))) uint32_t*)(uintptr_t)l,
        16, 0, 0);
}

// ---------------------------------------------------------------------------
// P1 + prep fused: dst-bucket histogram | fp32->bf16 conversions.
// ---------------------------------------------------------------------------
__global__ __launch_bounds__(256) void hist_prep_kernel(const int* __restrict__ dst,
                                                        int* __restrict__ hist,
                                                        const float* __restrict__ x,
                                                        u16* __restrict__ xb,
                                                        const float* __restrict__ W1,
                                                        u16* __restrict__ W1t,
                                                        const float* __restrict__ W2,
                                                        u16* __restrict__ W2t) {
    const int b = blockIdx.x;
    const int t = threadIdx.x;
    if (b < NB_PART) {
        __shared__ int h[256];
        h[t] = 0;
        __syncthreads();
        const int base = b * EPB;
        #pragma unroll
        for (int i = 0; i < EPB / 256; ++i) {
            const int e = base + i * 256 + t;
            if (e < N_EDGES) atomicAdd(&h[dst[e] >> 8], 1);
        }
        __syncthreads();
        hist[b * 256 + t] = h[t];
    } else if (b < NB_PART + NB_F2BF) {
        const int i = (b - NB_PART) * 256 + t;
        float4 v = *reinterpret_cast<const float4*>(&x[(size_t)i * 4]);
        ushort4v o;
        o.x = f2bf(v.x); o.y = f2bf(v.y); o.z = f2bf(v.z); o.w = f2bf(v.w);
        *reinterpret_cast<ushort4v*>(&xb[(size_t)i * 4]) = o;
    } else if (b < NB_PART + NB_F2BF + 256) {
        const int n = b - (NB_PART + NB_F2BF);
        W1t[(size_t)n * 256 + t] = f2bf(W1[(size_t)t * N_COLS + n]);
    } else {
        const int n = b - (NB_PART + NB_F2BF + 256);
        #pragma unroll
        for (int kk = 0; kk < 2; ++kk) {
            const int k = kk * 256 + t;
            W2t[(size_t)n * 512 + k] = f2bf(W2[(size_t)k * N_COLS + n]);
        }
    }
}

// S1: per-bin scan across 196 rows (works for edge hist and node-deg hist).
__global__ __launch_bounds__(256) void colscan_kernel(int* __restrict__ hist,
                                                      int* __restrict__ bin_tot) {
    __shared__ int s[256];
    const int b = blockIdx.x;
    const int t = threadIdx.x;
    const int v = (t < NB_PART) ? hist[t * 256 + b] : 0;
    s[t] = v;
    __syncthreads();
    #pragma unroll
    for (int o = 1; o < 256; o <<= 1) {
        int tv = 0;
        if (t >= o) tv = s[t - o];
        __syncthreads();
        s[t] += tv;
        __syncthreads();
    }
    if (t < NB_PART) hist[t * 256 + b] = s[t] - v;
    if (t == 255) bin_tot[b] = s[255];
}

// S2 (edge version): scan NBUCK totals -> bin_base; set row_ptr[N].
__global__ __launch_bounds__(256) void binscan_kernel(const int* __restrict__ bin_tot,
                                                      int* __restrict__ bin_base,
                                                      int* __restrict__ row_ptr) {
    __shared__ int s[256];
    const int t = threadIdx.x;
    const int v = (t < NBUCK) ? bin_tot[t] : 0;
    s[t] = v;
    __syncthreads();
    #pragma unroll
    for (int o = 1; o < 256; o <<= 1) {
        int tv = 0;
        if (t >= o) tv = s[t - o];
        __syncthreads();
        s[t] += tv;
        __syncthreads();
    }
    bin_base[t] = s[t] - v;
    if (t == 0) row_ptr[N_NODES] = N_EDGES;
}

// S2b (degree version): scan all 256 totals -> base.
__global__ __launch_bounds__(256) void binscan256_kernel(const int* __restrict__ tot,
                                                         int* __restrict__ base) {
    __shared__ int s[256];
    const int t = threadIdx.x;
    const int v = tot[t];
    s[t] = v;
    __syncthreads();
    #pragma unroll
    for (int o = 1; o < 256; o <<= 1) {
        int tv = 0;
        if (t >= o) tv = s[t - o];
        __syncthreads();
        s[t] += tv;
        __syncthreads();
    }
    base[t] = s[t] - v;
}

// P2: partition edges into bucket-contiguous ebuf (packed: src | dstLow<<16).
__global__ __launch_bounds__(256) void scatter_kernel(const int* __restrict__ src,
                                                      const int* __restrict__ dst,
                                                      const int* __restrict__ hist,
                                                      const int* __restrict__ bin_base,
                                                      int* __restrict__ ebuf) {
    __shared__ int cur[256];
    const int t = threadIdx.x;
    cur[t] = bin_base[t] + hist[blockIdx.x * 256 + t];
    __syncthreads();
    const int base = blockIdx.x * EPB;
    #pragma unroll
    for (int i = 0; i < EPB / 256; ++i) {
        const int e = base + i * 256 + t;
        if (e < N_EDGES) {
            const int d = dst[e];
            const int pos = atomicAdd(&cur[d >> 8], 1);
            ebuf[pos] = (src[e] & 0xFFFF) | ((d & 255) << 16);
        }
    }
}

// P3: per bucket: deg-count -> scan -> row_ptr/inv_deg -> col fill.
// Also LDS degree histogram -> nhist[block][bin] (NO global atomics).
__global__ __launch_bounds__(256) void bucket_fill_kernel(const int* __restrict__ ebuf,
                                                          const int* __restrict__ bin_base,
                                                          int* __restrict__ row_ptr,
                                                          float* __restrict__ inv_deg,
                                                          int* __restrict__ col,
                                                          int* __restrict__ nhist) {
    __shared__ int cnt[256];
    __shared__ int scn[256];
    __shared__ int cur[256];
    __shared__ int dh[256];
    const int blk = blockIdx.x;
    const int t = threadIdx.x;
    const int ebeg = bin_base[blk];
    const int eend = bin_base[blk + 1];
    const int nb0 = blk << 8;

    cnt[t] = 0;
    dh[t] = 0;
    __syncthreads();
    for (int e = ebeg + t; e < eend; e += 256)
        atomicAdd(&cnt[(ebuf[e] >> 16) & 255], 1);
    __syncthreads();
    const int d = cnt[t];
    scn[t] = d;
    __syncthreads();
    #pragma unroll
    for (int o = 1; o < 256; o <<= 1) {
        int tv = 0;
        if (t >= o) tv = scn[t - o];
        __syncthreads();
        scn[t] += tv;
        __syncthreads();
    }
    const int off = scn[t] - d;
    const int n = nb0 + t;
    if (n < N_NODES) {
        row_ptr[n] = ebeg + off;
        inv_deg[n] = (d > 0) ? (1.0f / (float)d) : 0.0f;
        atomicAdd(&dh[d < 255 ? d : 255], 1);   // LDS only
    }
    cur[t] = off;
    __syncthreads();
    nhist[blk * 256 + t] = dh[t];
    for (int e = ebeg + t; e < eend; e += 256) {
        const int p = ebuf[e];
        col[ebeg + atomicAdd(&cur[(p >> 16) & 255], 1)] = p & 0xFFFF;
    }
}

// D2: node order by degree: LDS local rank + per-(block,bin) base.
__global__ __launch_bounds__(256) void norder_kernel(const int* __restrict__ rp,
                                                     const int* __restrict__ nhist,
                                                     const int* __restrict__ nbase,
                                                     int* __restrict__ order) {
    __shared__ int lc[256];
    const int b = blockIdx.x;
    const int t = threadIdx.x;
    lc[t] = 0;
    __syncthreads();
    const int n = b * 256 + t;
    if (n < N_NODES) {
        int d = rp[n + 1] - rp[n];
        if (d > 255) d = 255;
        const int r = atomicAdd(&lc[d], 1);   // LDS only
        order[nbase[d] + nhist[b * 256 + d] + r] = n;
    }
}

// ---------------------------------------------------------------------------
// Column-sliced, XCD-pinned, degree-sorted mean aggregation (round-13 agg body).
// ---------------------------------------------------------------------------
template <int F, int SLICES>
__global__ __launch_bounds__(256) void agg_mean_sliced(const u16* __restrict__ feat,
                                                       const int* __restrict__ rp,
                                                       const int* __restrict__ col,
                                                       const float* __restrict__ invd,
                                                       const int* __restrict__ order,
                                                       u16* __restrict__ out) {
    constexpr int SC  = F / SLICES;                    // 64 cols = 128B slice
    static_assert(SC == 64, "slice must be one 128B line");
    constexpr int LPN = SC / 8;
    constexpr int NPB = 256 / LPN;                     // 32 nodes per block
    constexpr int XPS = 8 / SLICES;
    constexpr int NCHUNK = (N_NODES + NPB - 1) / NPB;
    constexpr int CPX    = (NCHUNK + XPS - 1) / XPS;
    const int bid  = blockIdx.x;
    const int x    = bid & 7;
    const int s    = x / XPS;
    const int part = x % XPS;
    const int chunk = part * CPX + (bid >> 3);
    const int slot = threadIdx.x / LPN;
    const int ln   = threadIdx.x % LPN;
    const int gs = chunk * NPB + slot;
    if (gs >= N_NODES) return;
    const int n = order[gs];

    const u16* ft = feat + s * SC + ln * 8;
    const int beg = rp[n], end = rp[n + 1];
    float acc0[8] = {}, acc1[8] = {};
    int e = beg;
    for (; e + 3 < end; e += 4) {
        int nb0 = col[e];
        int nb1 = col[e + 1];
        int nb2 = col[e + 2];
        int nb3 = col[e + 3];
        ushort8v v0 = *reinterpret_cast<const ushort8v*>(&ft[(size_t)nb0 * F]);
        ushort8v v1 = *reinterpret_cast<const ushort8v*>(&ft[(size_t)nb1 * F]);
        ushort8v v2 = *reinterpret_cast<const ushort8v*>(&ft[(size_t)nb2 * F]);
        ushort8v v3 = *reinterpret_cast<const ushort8v*>(&ft[(size_t)nb3 * F]);
        #pragma unroll
        for (int j = 0; j < 8; ++j) acc0[j] += bf2f(v0[j]);
        #pragma unroll
        for (int j = 0; j < 8; ++j) acc1[j] += bf2f(v1[j]);
        #pragma unroll
        for (int j = 0; j < 8; ++j) acc0[j] += bf2f(v2[j]);
        #pragma unroll
        for (int j = 0; j < 8; ++j) acc1[j] += bf2f(v3[j]);
    }
    if (e + 1 < end) {
        int nb0 = col[e];
        int nb1 = col[e + 1];
        ushort8v v0 = *reinterpret_cast<const ushort8v*>(&ft[(size_t)nb0 * F]);
        ushort8v v1 = *reinterpret_cast<const ushort8v*>(&ft[(size_t)nb1 * F]);
        #pragma unroll
        for (int j = 0; j < 8; ++j) acc0[j] += bf2f(v0[j]);
        #pragma unroll
        for (int j = 0; j < 8; ++j) acc1[j] += bf2f(v1[j]);
        e += 2;
    }
    if (e < end) {
        ushort8v v = *reinterpret_cast<const ushort8v*>(&ft[(size_t)col[e] * F]);
        #pragma unroll
        for (int j = 0; j < 8; ++j) acc0[j] += bf2f(v[j]);
    }
    const float sc = invd[n];
    ushort8v o;
    #pragma unroll
    for (int j = 0; j < 8; ++j) o[j] = f2bf((acc0[j] + acc1[j]) * sc);
    *reinterpret_cast<ushort8v*>(&out[(size_t)n * F + s * SC + ln * 8]) = o;
}

// ---------------------------------------------------------------------------
// GEMM: BK=64 + both-sides XOR swizzle (round-12 verbatim).
// ---------------------------------------------------------------------------
template <int K1, bool OUT_BF16>
__global__ __launch_bounds__(256) void gemm_bt_bf16(const u16* __restrict__ A1,
                                                    const u16* __restrict__ A2,
                                                    const u16* __restrict__ Bt,
                                                    const float* __restrict__ bias,
                                                    void* __restrict__ Cout, int M) {
    constexpr int K = 2 * K1;
    __shared__ u16 As[128 * 64];
    __shared__ u16 Bs[128 * 64];

    const int t  = threadIdx.x;
    const int wv = t >> 6;
    const int l  = t & 63;
    const int g  = blockIdx.x >> 4;
    const int r  = blockIdx.x & 15;
    const int m0 = (g * 8 + (r & 7)) * 128;
    const int n0 = (r >> 3) * 128;

    const int srow = l >> 3;
    const int sjj  = ((l & 7) ^ srow) * 8;

    const int lr  = l & 15;
    const int l4  = l >> 4;
    const int wr  = (wv >> 1) * 64;
    const int wc  = (wv & 1) * 64;
    const int swz = lr & 7;

    f32x4 acc[4][4] = {};

    #pragma unroll 1
    for (int kt = 0; kt < K / 64; ++kt) {
        const int kg = kt * 64;
        const u16* Ab;
        int ka;
        if (kg < K1) { Ab = A1; ka = kg; }
        else         { Ab = A2; ka = kg - K1; }

        #pragma unroll
        for (int i = 0; i < 4; ++i) {
            const int rowg = wv * 32 + i * 8;
            gll16(&Ab[(size_t)(m0 + rowg + srow) * K1 + ka + sjj], &As[rowg * 64]);
            gll16(&Bt[(size_t)(n0 + rowg + srow) * K  + kg + sjj], &Bs[rowg * 64]);
        }
        __syncthreads();

        #pragma unroll
        for (int kk2 = 0; kk2 < 2; ++kk2) {
            const int jc = ((kk2 * 4 + l4) ^ swz) * 8;
            bf16x8 af[4], bfr[4];
            #pragma unroll
            for (int m = 0; m < 4; ++m)
                af[m] = *reinterpret_cast<const bf16x8*>(&As[(wr + m * 16 + lr) * 64 + jc]);
            #pragma unroll
            for (int n = 0; n < 4; ++n)
                bfr[n] = *reinterpret_cast<const bf16x8*>(&Bs[(wc + n * 16 + lr) * 64 + jc]);
            #pragma unroll
            for (int m = 0; m < 4; ++m)
                #pragma unroll
                for (int n = 0; n < 4; ++n)
                    acc[m][n] = __builtin_amdgcn_mfma_f32_16x16x32_bf16(af[m], bfr[n], acc[m][n], 0, 0, 0);
        }
        __syncthreads();
    }

    const int orow = (l >> 4) * 4;
    float bcol[4];
    #pragma unroll
    for (int n = 0; n < 4; ++n) bcol[n] = bias[n0 + wc + n * 16 + lr];

    #pragma unroll
    for (int m = 0; m < 4; ++m) {
        #pragma unroll
        for (int r2 = 0; r2 < 4; ++r2) {
            const int row = m0 + wr + m * 16 + orow + r2;
            if (row < M) {
                #pragma unroll
                for (int n = 0; n < 4; ++n) {
                    const int cg = n0 + wc + n * 16 + lr;
                    float v = fmaxf(acc[m][n][r2] + bcol[n], 0.f);
                    if (OUT_BF16)
                        ((u16*)Cout)[(size_t)row * N_COLS + cg] = f2bf(v);
                    else
                        ((float*)Cout)[(size_t)row * N_COLS + cg] = v;
                }
            }
        }
    }
}

// ---------------------------------------------------------------------------
// Host launch
// ---------------------------------------------------------------------------
extern "C" void kernel_launch(void* const* d_in, const int* in_sizes, int n_in,
                              void* d_out, int out_size, void* d_ws, size_t ws_size,
                              hipStream_t stream) {
    const float* x   = (const float*)d_in[0];
    const int*   src = (const int*)d_in[1];
    const int*   dst = (const int*)d_in[2];
    const float* W1  = (const float*)d_in[3];
    const float* b1  = (const float*)d_in[4];
    const float* W2  = (const float*)d_in[5];
    const float* b2  = (const float*)d_in[6];
    float* out = (float*)d_out;

    char* ws = (char*)d_ws;
    size_t off = 0;
    auto carve = [&](size_t bytes) {
        char* p = ws + off;
        off = (off + bytes + 255) & ~(size_t)255;
        return p;
    };
    int*   row_ptr  = (int*)carve(sizeof(int) * (N_NODES + 1));
    float* inv_deg  = (float*)carve(sizeof(float) * N_NODES);
    int*   col      = (int*)carve(sizeof(int) * N_EDGES);
    int*   hist     = (int*)carve(sizeof(int) * NB_PART * 256);
    int*   bin_tot  = (int*)carve(sizeof(int) * 256);
    int*   bin_base = (int*)carve(sizeof(int) * 256);
    int*   nhist    = (int*)carve(sizeof(int) * NBUCK * 256);
    int*   ntot     = (int*)carve(sizeof(int) * 256);
    int*   nbase    = (int*)carve(sizeof(int) * 256);
    int*   order    = (int*)carve(sizeof(int) * N_NODES);
    int*   ebuf     = (int*)carve(sizeof(int) * N_EDGES);
    u16*   xb       = (u16*)carve(sizeof(u16) * (size_t)M_PAD * F_IN);
    u16*   xnb      = (u16*)carve(sizeof(u16) * (size_t)M_PAD * F_IN);
    u16*   h1b      = (u16*)carve(sizeof(u16) * (size_t)M_PAD * F_HID);
    u16*   h1nb     = (u16*)carve(sizeof(u16) * (size_t)M_PAD * F_HID);
    u16*   W1t      = (u16*)carve(sizeof(u16) * 256 * 256);
    u16*   W2t      = (u16*)carve(sizeof(u16) * 256 * 512);

    // --- CSR build + conversions ---
    hist_prep_kernel<<<dim3(NB_PART + NB_F2BF + 512), 256, 0, stream>>>(
        dst, hist, x, xb, W1, W1t, W2, W2t);
    colscan_kernel<<<dim3(NBUCK), 256, 0, stream>>>(hist, bin_tot);
    binscan_kernel<<<dim3(1), 256, 0, stream>>>(bin_tot, bin_base, row_ptr);
    scatter_kernel<<<dim3(NB_PART), 256, 0, stream>>>(src, dst, hist, bin_base, ebuf);
    bucket_fill_kernel<<<dim3(NBUCK), 256, 0, stream>>>(ebuf, bin_base, row_ptr, inv_deg, col, nhist);

    // --- node degree sort (contention-free counting sort) ---
    colscan_kernel<<<dim3(256), 256, 0, stream>>>(nhist, ntot);
    binscan256_kernel<<<dim3(1), 256, 0, stream>>>(ntot, nbase);
    norder_kernel<<<dim3(NBUCK), 256, 0, stream>>>(row_ptr, nhist, nbase, order);

    // --- Layer 1: 64-col slices (2 slices, 4 XCDs each) ---
    {
        constexpr int NPB = 32, XPS = 4;
        constexpr int CPX = (((N_NODES + NPB - 1) / NPB) + XPS - 1) / XPS;   // 391
        agg_mean_sliced<F_IN, 2><<<dim3(8 * CPX), 256, 0, stream>>>(
            xb, row_ptr, col, inv_deg, order, xnb);
    }
    gemm_bt_bf16<128, true><<<dim3(784), 256, 0, stream>>>(xb, xnb, W1t, b1, h1b, N_NODES);

    // --- Layer 2: 64-col slices (4 slices, 2 XCDs each) ---
    {
        constexpr int NPB = 32, XPS = 2;
        constexpr int CPX = (((N_NODES + NPB - 1) / NPB) + XPS - 1) / XPS;   // 782
        agg_mean_sliced<F_HID, 4><<<dim3(8 * CPX), 256, 0, stream>>>(
            h1b, row_ptr, col, inv_deg, order, h1nb);
    }
    gemm_bt_bf16<256, false><<<dim3(784), 256, 0, stream>>>(h1b, h1nb, W2t, b2, out, N_NODES);
}

// Round 15
// 164.462 us; speedup vs baseline: 2.6644x; 1.1089x over previous
//
#include <hip/hip_runtime.h>
#include <hip/hip_bf16.h>
#include <cstdint>

constexpr int N_NODES = 50000;
constexpr int N_EDGES = 800000;
constexpr int F_IN    = 128;
constexpr int F_HID   = 256;
constexpr int N_COLS  = 256;
constexpr int M_PAD   = 50176;   // 392 * 128
constexpr int NB_F2BF = (N_NODES * F_IN / 4) / 256;  // 6250 (exact)

// CSR build via bucketed counting sort (single dst pass — round-9/12 config)
constexpr int EPB     = 4096;
constexpr int NB_PART = (N_EDGES + EPB - 1) / EPB;    // 196
constexpr int NBUCK   = (N_NODES + 255) / 256;        // 196

typedef unsigned short u16;
typedef u16   ushort4v __attribute__((ext_vector_type(4)));
typedef u16   ushort8v __attribute__((ext_vector_type(8)));
typedef __bf16 bf16x8  __attribute__((ext_vector_type(8)));
typedef float  f32x4   __attribute__((ext_vector_type(4)));

__device__ __forceinline__ float bf2f(u16 u) {
    return __uint_as_float(((uint32_t)u) << 16);
}
__device__ __forceinline__ u16 f2bf(float f) {
    uint32_t u = __float_as_uint(f);
    uint32_t r = u + 0x7FFFu + ((u >> 16) & 1u);   // RNE
    return (u16)(r >> 16);
}

// async global->LDS, 16B per lane. LDS dest is wave-uniform base; HW adds lane*16.
__device__ __forceinline__ void gll16(const void* g, void* l) {
    __builtin_amdgcn_global_load_lds(
        (const __attribute__((address_space(1))) uint32_t*)(uintptr_t)g,
        (__attribute__((address_space(3))) uint32_t*)(uintptr_t)l,
        16, 0, 0);
}

// ---------------------------------------------------------------------------
// P1: per-block bucket histogram (LDS only).
// ---------------------------------------------------------------------------
__global__ __launch_bounds__(256) void hist_kernel(const int* __restrict__ dst,
                                                   int* __restrict__ hist) {
    __shared__ int h[256];
    const int t = threadIdx.x;
    h[t] = 0;
    __syncthreads();
    const int base = blockIdx.x * EPB;
    #pragma unroll
    for (int i = 0; i < EPB / 256; ++i) {
        const int e = base + i * 256 + t;
        if (e < N_EDGES) atomicAdd(&h[dst[e] >> 8], 1);
    }
    __syncthreads();
    hist[blockIdx.x * 256 + t] = h[t];
}

// S1: per-bin scan across blocks.
__global__ __launch_bounds__(256) void colscan_kernel(int* __restrict__ hist,
                                                      int* __restrict__ bin_tot) {
    __shared__ int s[256];
    const int b = blockIdx.x;
    const int t = threadIdx.x;
    const int v = (t < NB_PART) ? hist[t * 256 + b] : 0;
    s[t] = v;
    __syncthreads();
    #pragma unroll
    for (int o = 1; o < 256; o <<= 1) {
        int tv = 0;
        if (t >= o) tv = s[t - o];
        __syncthreads();
        s[t] += tv;
        __syncthreads();
    }
    if (t < NB_PART) hist[t * 256 + b] = s[t] - v;
    if (t == 255) bin_tot[b] = s[255];
}

// S2: exclusive scan of bin totals -> bin_base.
__global__ __launch_bounds__(256) void binscan_kernel(const int* __restrict__ bin_tot,
                                                      int* __restrict__ bin_base,
                                                      int* __restrict__ row_ptr) {
    __shared__ int s[256];
    const int t = threadIdx.x;
    const int v = (t < NBUCK) ? bin_tot[t] : 0;
    s[t] = v;
    __syncthreads();
    #pragma unroll
    for (int o = 1; o < 256; o <<= 1) {
        int tv = 0;
        if (t >= o) tv = s[t - o];
        __syncthreads();
        s[t] += tv;
        __syncthreads();
    }
    bin_base[t] = s[t] - v;
    if (t == 0) row_ptr[N_NODES] = N_EDGES;
}

// P2: partition edges into bucket-contiguous ebuf.
__global__ __launch_bounds__(256) void scatter_kernel(const int* __restrict__ src,
                                                      const int* __restrict__ dst,
                                                      const int* __restrict__ hist,
                                                      const int* __restrict__ bin_base,
                                                      int2* __restrict__ ebuf) {
    __shared__ int cur[256];
    const int t = threadIdx.x;
    cur[t] = bin_base[t] + hist[blockIdx.x * 256 + t];
    __syncthreads();
    const int base = blockIdx.x * EPB;
    #pragma unroll
    for (int i = 0; i < EPB / 256; ++i) {
        const int e = base + i * 256 + t;
        if (e < N_EDGES) {
            const int d = dst[e];
            const int pos = atomicAdd(&cur[d >> 8], 1);
            ebuf[pos] = make_int2(src[e], d);
        }
    }
}

// P3: one block per bucket: deg-count -> scan -> row_ptr/inv_deg -> col fill.
__global__ __launch_bounds__(256) void bucket_fill_kernel(const int2* __restrict__ ebuf,
                                                          const int* __restrict__ bin_base,
                                                          int* __restrict__ row_ptr,
                                                          float* __restrict__ inv_deg,
                                                          int* __restrict__ col) {
    __shared__ int cnt[256];
    __shared__ int scn[256];
    __shared__ int cur[256];
    const int blk = blockIdx.x;
    const int t = threadIdx.x;
    const int ebeg = bin_base[blk];
    const int eend = bin_base[blk + 1];
    const int nb0 = blk << 8;

    cnt[t] = 0;
    __syncthreads();
    for (int e = ebeg + t; e < eend; e += 256)
        atomicAdd(&cnt[ebuf[e].y & 255], 1);
    __syncthreads();
    const int d = cnt[t];
    scn[t] = d;
    __syncthreads();
    #pragma unroll
    for (int o = 1; o < 256; o <<= 1) {
        int tv = 0;
        if (t >= o) tv = scn[t - o];
        __syncthreads();
        scn[t] += tv;
        __syncthreads();
    }
    const int off = scn[t] - d;
    const int n = nb0 + t;
    if (n < N_NODES) {
        row_ptr[n] = ebeg + off;
        inv_deg[n] = (d > 0) ? (1.0f / (float)d) : 0.0f;
    }
    cur[t] = off;
    __syncthreads();
    for (int e = ebeg + t; e < eend; e += 256) {
        const int2 p = ebuf[e];
        col[ebeg + atomicAdd(&cur[p.y & 255], 1)] = p.x;
    }
}

// ---------------------------------------------------------------------------
// prep: x fp32 -> xb bf16  |  W1 -> W1t (transposed bf16)  |  W2 -> W2t
// ---------------------------------------------------------------------------
__global__ __launch_bounds__(256) void prep_kernel(const float* __restrict__ x,
                                                   u16* __restrict__ xb,
                                                   const float* __restrict__ W1,
                                                   u16* __restrict__ W1t,
                                                   const float* __restrict__ W2,
                                                   u16* __restrict__ W2t) {
    const int b = blockIdx.x;
    const int tid = threadIdx.x;
    if (b < NB_F2BF) {
        const int i = b * 256 + tid;   // float4 index
        float4 v = *reinterpret_cast<const float4*>(&x[(size_t)i * 4]);
        ushort4v o;
        o.x = f2bf(v.x); o.y = f2bf(v.y); o.z = f2bf(v.z); o.w = f2bf(v.w);
        *reinterpret_cast<ushort4v*>(&xb[(size_t)i * 4]) = o;
    } else if (b < NB_F2BF + 256) {
        const int n = b - NB_F2BF;
        W1t[(size_t)n * 256 + tid] = f2bf(W1[(size_t)tid * N_COLS + n]);
    } else {
        const int n = b - (NB_F2BF + 256);
        #pragma unroll
        for (int kk = 0; kk < 2; ++kk) {
            const int k = kk * 256 + tid;
            W2t[(size_t)n * 512 + k] = f2bf(W2[(size_t)k * N_COLS + n]);
        }
    }
}

// ---------------------------------------------------------------------------
// Column-sliced, XCD-pinned mean aggregation (round-9/12 verbatim — at the
// per-CU vmem-issue floor; five probes say do not touch).
// ---------------------------------------------------------------------------
template <int F, int SLICES>
__global__ __launch_bounds__(256) void agg_mean_sliced(const u16* __restrict__ feat,
                                                       const int* __restrict__ rp,
                                                       const int* __restrict__ col,
                                                       const float* __restrict__ invd,
                                                       u16* __restrict__ out) {
    constexpr int SC  = F / SLICES;                    // 64 cols = 128B slice
    static_assert(SC == 64, "slice must be one 128B line");
    constexpr int LPN = SC / 8;                        // 8 lanes per node
    constexpr int NPB = 256 / LPN;                     // 32 nodes per block
    constexpr int XPS = 8 / SLICES;                    // XCDs per slice
    constexpr int NCHUNK = (N_NODES + NPB - 1) / NPB;  // 1563
    constexpr int CPX    = (NCHUNK + XPS - 1) / XPS;
    const int bid  = blockIdx.x;
    const int x    = bid & 7;
    const int s    = x / XPS;
    const int part = x % XPS;
    const int chunk = part * CPX + (bid >> 3);
    const int slot = threadIdx.x / LPN;
    const int ln   = threadIdx.x % LPN;
    const int n = chunk * NPB + slot;
    if (n >= N_NODES) return;

    const u16* ft = feat + s * SC + ln * 8;
    const int beg = rp[n], end = rp[n + 1];
    float acc0[8] = {}, acc1[8] = {};
    int e = beg;
    for (; e + 3 < end; e += 4) {
        int nb0 = col[e];
        int nb1 = col[e + 1];
        int nb2 = col[e + 2];
        int nb3 = col[e + 3];
        ushort8v v0 = *reinterpret_cast<const ushort8v*>(&ft[(size_t)nb0 * F]);
        ushort8v v1 = *reinterpret_cast<const ushort8v*>(&ft[(size_t)nb1 * F]);
        ushort8v v2 = *reinterpret_cast<const ushort8v*>(&ft[(size_t)nb2 * F]);
        ushort8v v3 = *reinterpret_cast<const ushort8v*>(&ft[(size_t)nb3 * F]);
        #pragma unroll
        for (int j = 0; j < 8; ++j) acc0[j] += bf2f(v0[j]);
        #pragma unroll
        for (int j = 0; j < 8; ++j) acc1[j] += bf2f(v1[j]);
        #pragma unroll
        for (int j = 0; j < 8; ++j) acc0[j] += bf2f(v2[j]);
        #pragma unroll
        for (int j = 0; j < 8; ++j) acc1[j] += bf2f(v3[j]);
    }
    if (e + 1 < end) {
        int nb0 = col[e];
        int nb1 = col[e + 1];
        ushort8v v0 = *reinterpret_cast<const ushort8v*>(&ft[(size_t)nb0 * F]);
        ushort8v v1 = *reinterpret_cast<const ushort8v*>(&ft[(size_t)nb1 * F]);
        #pragma unroll
        for (int j = 0; j < 8; ++j) acc0[j] += bf2f(v0[j]);
        #pragma unroll
        for (int j = 0; j < 8; ++j) acc1[j] += bf2f(v1[j]);
        e += 2;
    }
    if (e < end) {
        ushort8v v = *reinterpret_cast<const ushort8v*>(&ft[(size_t)col[e] * F]);
        #pragma unroll
        for (int j = 0; j < 8; ++j) acc0[j] += bf2f(v[j]);
    }
    const float sc = invd[n];
    ushort8v o;
    #pragma unroll
    for (int j = 0; j < 8; ++j) o[j] = f2bf((acc0[j] + acc1[j]) * sc);
    *reinterpret_cast<ushort8v*>(&out[(size_t)n * F + s * SC + ln * 8]) = o;
}

// ---------------------------------------------------------------------------
// C = relu([A1 | A2] @ W + b), bf16 MFMA. BK=64 + both-sides XOR swizzle
// (round-12 verbatim — validated at 164.9 µs total).
// ---------------------------------------------------------------------------
template <int K1, bool OUT_BF16>
__global__ __launch_bounds__(256) void gemm_bt_bf16(const u16* __restrict__ A1,
                                                    const u16* __restrict__ A2,
                                                    const u16* __restrict__ Bt,
                                                    const float* __restrict__ bias,
                                                    void* __restrict__ Cout, int M) {
    constexpr int K = 2 * K1;
    __shared__ u16 As[128 * 64];   // 16 KB, swizzled image
    __shared__ u16 Bs[128 * 64];   // 16 KB

    const int t  = threadIdx.x;
    const int wv = t >> 6;
    const int l  = t & 63;
    const int g  = blockIdx.x >> 4;
    const int r  = blockIdx.x & 15;
    const int m0 = (g * 8 + (r & 7)) * 128;
    const int n0 = (r >> 3) * 128;

    // staging coords: 8 rows per gll (8 lanes x 16B each row)
    const int srow = l >> 3;                   // row within 8-row group
    const int sjj  = ((l & 7) ^ srow) * 8;     // swizzled k-element offset

    // fragment coords
    const int lr  = l & 15;
    const int l4  = l >> 4;                    // 0..3
    const int wr  = (wv >> 1) * 64;
    const int wc  = (wv & 1) * 64;
    const int swz = lr & 7;

    f32x4 acc[4][4] = {};

    #pragma unroll 1
    for (int kt = 0; kt < K / 64; ++kt) {
        const int kg = kt * 64;
        const u16* Ab;
        int ka;
        if (kg < K1) { Ab = A1; ka = kg; }
        else         { Ab = A2; ka = kg - K1; }

        #pragma unroll
        for (int i = 0; i < 4; ++i) {
            const int rowg = wv * 32 + i * 8;              // LDS row-group base
            gll16(&Ab[(size_t)(m0 + rowg + srow) * K1 + ka + sjj], &As[rowg * 64]);
            gll16(&Bt[(size_t)(n0 + rowg + srow) * K  + kg + sjj], &Bs[rowg * 64]);
        }
        __syncthreads();

        #pragma unroll
        for (int kk2 = 0; kk2 < 2; ++kk2) {
            const int jc = ((kk2 * 4 + l4) ^ swz) * 8;     // un-swizzled chunk
            bf16x8 af[4], bfr[4];
            #pragma unroll
            for (int m = 0; m < 4; ++m)
                af[m] = *reinterpret_cast<const bf16x8*>(&As[(wr + m * 16 + lr) * 64 + jc]);
            #pragma unroll
            for (int n = 0; n < 4; ++n)
                bfr[n] = *reinterpret_cast<const bf16x8*>(&Bs[(wc + n * 16 + lr) * 64 + jc]);
            #pragma unroll
            for (int m = 0; m < 4; ++m)
                #pragma unroll
                for (int n = 0; n < 4; ++n)
                    acc[m][n] = __builtin_amdgcn_mfma_f32_16x16x32_bf16(af[m], bfr[n], acc[m][n], 0, 0, 0);
        }
        __syncthreads();
    }

    const int orow = (l >> 4) * 4;
    float bcol[4];
    #pragma unroll
    for (int n = 0; n < 4; ++n) bcol[n] = bias[n0 + wc + n * 16 + lr];

    #pragma unroll
    for (int m = 0; m < 4; ++m) {
        #pragma unroll
        for (int r2 = 0; r2 < 4; ++r2) {
            const int row = m0 + wr + m * 16 + orow + r2;
            if (row < M) {
                #pragma unroll
                for (int n = 0; n < 4; ++n) {
                    const int cg = n0 + wc + n * 16 + lr;
                    float v = fmaxf(acc[m][n][r2] + bcol[n], 0.f);
                    if (OUT_BF16)
                        ((u16*)Cout)[(size_t)row * N_COLS + cg] = f2bf(v);
                    else
                        ((float*)Cout)[(size_t)row * N_COLS + cg] = v;
                }
            }
        }
    }
}

// ---------------------------------------------------------------------------
// Host launch
// ---------------------------------------------------------------------------
extern "C" void kernel_launch(void* const* d_in, const int* in_sizes, int n_in,
                              void* d_out, int out_size, void* d_ws, size_t ws_size,
                              hipStream_t stream) {
    const float* x   = (const float*)d_in[0];
    const int*   src = (const int*)d_in[1];
    const int*   dst = (const int*)d_in[2];
    const float* W1  = (const float*)d_in[3];
    const float* b1  = (const float*)d_in[4];
    const float* W2  = (const float*)d_in[5];
    const float* b2  = (const float*)d_in[6];
    float* out = (float*)d_out;

    char* ws = (char*)d_ws;
    size_t off = 0;
    auto carve = [&](size_t bytes) {
        char* p = ws + off;
        off = (off + bytes + 255) & ~(size_t)255;
        return p;
    };
    int*   row_ptr  = (int*)carve(sizeof(int) * (N_NODES + 1));
    float* inv_deg  = (float*)carve(sizeof(float) * N_NODES);
    int*   col      = (int*)carve(sizeof(int) * N_EDGES);
    int*   hist     = (int*)carve(sizeof(int) * NB_PART * 256);
    int*   bin_tot  = (int*)carve(sizeof(int) * 256);
    int*   bin_base = (int*)carve(sizeof(int) * 256);
    int2*  ebuf     = (int2*)carve(sizeof(int2) * N_EDGES);
    u16*   xb       = (u16*)carve(sizeof(u16) * (size_t)M_PAD * F_IN);
    u16*   xnb      = (u16*)carve(sizeof(u16) * (size_t)M_PAD * F_IN);
    u16*   h1b      = (u16*)carve(sizeof(u16) * (size_t)M_PAD * F_HID);
    u16*   h1nb     = (u16*)carve(sizeof(u16) * (size_t)M_PAD * F_HID);
    u16*   W1t      = (u16*)carve(sizeof(u16) * 256 * 256);
    u16*   W2t      = (u16*)carve(sizeof(u16) * 256 * 512);

    // --- CSR build: bucketed counting sort (single dst pass) ---
    hist_kernel<<<dim3(NB_PART), 256, 0, stream>>>(dst, hist);
    colscan_kernel<<<dim3(NBUCK), 256, 0, stream>>>(hist, bin_tot);
    binscan_kernel<<<dim3(1), 256, 0, stream>>>(bin_tot, bin_base, row_ptr);
    scatter_kernel<<<dim3(NB_PART), 256, 0, stream>>>(src, dst, hist, bin_base, ebuf);
    bucket_fill_kernel<<<dim3(NBUCK), 256, 0, stream>>>(ebuf, bin_base, row_ptr, inv_deg, col);

    // --- bf16 conversions ---
    prep_kernel<<<dim3(NB_F2BF + 512), 256, 0, stream>>>(x, xb, W1, W1t, W2, W2t);

    // --- Layer 1: 64-col slices (2 slices, 4 XCDs each) ---
    {
        constexpr int NPB = 32, XPS = 4;
        constexpr int CPX = (((N_NODES + NPB - 1) / NPB) + XPS - 1) / XPS;   // 391
        agg_mean_sliced<F_IN, 2><<<dim3(8 * CPX), 256, 0, stream>>>(
            xb, row_ptr, col, inv_deg, xnb);
    }
    gemm_bt_bf16<128, true><<<dim3(784), 256, 0, stream>>>(xb, xnb, W1t, b1, h1b, N_NODES);

    // --- Layer 2: 64-col slices (4 slices, 2 XCDs each) ---
    {
        constexpr int NPB = 32, XPS = 2;
        constexpr int CPX = (((N_NODES + NPB - 1) / NPB) + XPS - 1) / XPS;   // 782
        agg_mean_sliced<F_HID, 4><<<dim3(8 * CPX), 256, 0, stream>>>(
            h1b, row_ptr, col, inv_deg, h1nb);
    }
    gemm_bt_bf16<256, false><<<dim3(784), 256, 0, stream>>>(h1b, h1nb, W2t, b2, out, N_NODES);
}